// Round 18
// baseline (91.246 us; speedup 1.0000x reference)
//
#include <hip/hip_runtime.h>
#include <math.h>

#define NSTEP  730
#define NGRID  1500
#define LENF   15
#define PRECS  1e-5f
#define CH     16
#define NCHUNK 46                  // 45 full chunks + tail of 10
#define NPHASE (NCHUNK+3)          // 4-stage pipeline fill/drain
#define OTW    21                  // out-tile row: 20 + 1 pad

static __device__ __forceinline__ float fexp2(float v){ return __builtin_amdgcn_exp2f(v); }
static __device__ __forceinline__ float flog2(float v){ return __builtin_amdgcn_logf(v); }

// 16-lane sum via DPP xor-butterfly — pure VALU, result on all 16 lanes.
// (verified bit-stable vs reference in R4)
template<int CTRL>
static __device__ __forceinline__ float dpp_add(float v) {
    int t = __builtin_amdgcn_update_dpp(0, __float_as_int(v), CTRL, 0xF, 0xF, true);
    return v + __int_as_float(t);
}
static __device__ __forceinline__ float row16_sum(float v) {
    v = dpp_add<0xB1>(v);    // quad_perm [1,0,3,2]
    v = dpp_add<0x4E>(v);    // quad_perm [2,3,0,1]
    v = dpp_add<0x141>(v);   // row_half_mirror
    v = dpp_add<0x140>(v);   // row_mirror
    return v;
}

// Block = 256 threads = 4 waves = 4 pipeline stages over 4 grids, 375 blocks.
// R18: the mu-reduce moves INTO W2 as DPP (pure VALU) — the 64KB/phase of
// ds_read_b128 reduce traffic and the 33KB qbuf are deleted. Theory: the
// phase wall was per-CU LDS BANDWIDTH (~130KB/phase ≈ 2000cyc at 2 blk/CU),
// dominated by W3's reduce reads.
//   W0 snow(c) -> rt;  W1 soil(c-1) -> (re,ET);  W2 resp(c-2) + DPP-reduce
//   -> redbuf float4/(grid,step);  W3 epi(c-3): conv+store (1 task/lane).
__global__ __launch_bounds__(256, 1)
void hbv_scan_kernel(const float* __restrict__ x,       // (730,1500,3)
                     const float* __restrict__ params,  // (1500,12,16)
                     const float* __restrict__ rtwts,   // (1500,2)
                     float* __restrict__ out)           // (730,1500,5)
{
    __shared__ float  xring[3*CH*16];    //  3.0 KB (slot c%3)
    __shared__ float  rtbuf[2*CH*64];    //  8.0 KB
    __shared__ float2 soilbuf[2*CH*64];  // 16.0 KB (re, ETact)
    __shared__ float4 redbuf[2*CH*4];    //  2.0 KB (reduced sums per grid,step)
    __shared__ float  outtile[CH*OTW];   //  1.3 KB
    __shared__ float  ring[4*64];        //  1.0 KB  (total ~31.3 KB)

    const int tid  = threadIdx.x;
    const int wid  = tid >> 6;
    const int lane = tid & 63;
    const int gl = lane >> 4, m = lane & 15;
    const int b  = blockIdx.x;
    const int g  = b*4 + gl;
    const float inv16 = 1.f/16.f;

    // prestage chunk 0 (W3) + zero conv ring, one uniform barrier
    if (wid == 3) {
        #pragma unroll
        for (int j = 0; j < 3; ++j) {
            const int idx = lane + 64*j;
            const int r = idx/12, rem = idx - 12*r;
            const int gi = rem/3, ch = rem - 3*gi;
            xring[r*16 + gi*4 + ch] = x[r*4500 + b*12 + gi*3 + ch];
        }
    }
    ring[tid & 255] = 0.f;
    __syncthreads();

    if (wid == 0) {
        // ================= W0: snow recursion =================
        const float pTT     = -2.5f + params[(g*12+8)*16+m]*5.f;
        const float pCFMAX  =  0.5f + params[(g*12+9)*16+m]*9.5f;
        const float refCoef = (params[(g*12+10)*16+m]*0.1f)*pCFMAX;
        const float pCWH    =          params[(g*12+11)*16+m]*0.2f;
        const float negCMTT = -pCFMAX*pTT;
        const float refCTT  = refCoef*pTT;
        float SP = 0.001f, MW = 0.001f;
        for (int p = 0; p < NPHASE; ++p) {
            if (p < NCHUNK) {
                const float* xb = &xring[(p%3)*CH*16 + gl*4];
                float* rb = &rtbuf[(p&1)*CH*64 + lane];
                float2 PT[CH];
                #pragma unroll
                for (int s = 0; s < CH; ++s)
                    PT[s] = *(const float2*)(xb + s*16);
                #pragma unroll
                for (int s = 0; s < CH; ++s) {
                    const float Pm = PT[s].x, Tm = PT[s].y;
                    const float RAIN    = (Tm >= pTT) ? Pm : 0.f;
                    const float meltcap = fmaxf(fmaf(pCFMAX, Tm, negCMTT), 0.f);
                    const float refcap  = fmaxf(fmaf(-refCoef, Tm, refCTT), 0.f);
                    const float SP1 = SP + (Pm - RAIN);
                    const float melt = fminf(meltcap, SP1);
                    const float MW1 = MW + melt;
                    const float refreeze = fminf(refcap, MW1);
                    SP = SP1 - melt + refreeze;
                    const float MW2 = MW1 - refreeze;
                    const float tosoil = fmaxf(fmaf(-pCWH, SP, MW2), 0.f);
                    MW = MW2 - tosoil;
                    rb[s*64] = RAIN + tosoil;
                }
            }
            __syncthreads();
        }
    } else if (wid == 1) {
        // ================= W1: soil (SM) recursion =================
        const float bb  = 1.f  + params[(g*12+0)*16+m]*5.f;
        const float pFC = 50.f + params[(g*12+1)*16+m]*950.f;
        const float pLP = 0.2f + params[(g*12+5)*16+m]*0.8f;
        const float iLPFC = 1.f/(pLP*pFC);
        const float cc = -bb * flog2(pFC);       // sw = exp2(bb*log2(SM)+cc)
        float SM = 0.001f;
        for (int p = 0; p < NPHASE; ++p) {
            if (p >= 1 && p-1 < NCHUNK) {
                const int c = p-1;
                const float* xe = &xring[(c%3)*CH*16 + gl*4 + 2];
                const float* rb = &rtbuf[(c&1)*CH*64 + lane];
                float2* sb = &soilbuf[(c&1)*CH*64 + lane];
                float rt[CH], Ev[CH];
                #pragma unroll
                for (int s = 0; s < CH; ++s) { rt[s] = rb[s*64]; Ev[s] = xe[s*16]; }
                #pragma unroll
                for (int s = 0; s < CH; ++s) {
                    const float sw  = fexp2(fmaf(bb, flog2(SM), cc));
                    const float SM1 = fmaf(-rt[s], sw, SM + rt[s]);
                    const float SM2 = fminf(SM1, pFC);
                    const float cE  = Ev[s] * iLPFC;
                    const float et  = fminf(fminf(SM2*cE, SM2), Ev[s]);  // v_min3
                    const float re  = fmaf(rt[s], sw, SM1 - SM2);
                    SM = fmaxf(fmaxf(fmaf(-SM2, cE, SM2), SM2 - Ev[s]), PRECS);
                    sb[s*64] = make_float2(re, et);
                }
            }
            __syncthreads();
        }
    } else if (wid == 2) {
        // ======== W2: response recursion + DPP mu-reduce (pure VALU) ========
        const float pK0   = 0.05f  + params[(g*12+2)*16+m]*0.85f;
        const float pK1   = 0.01f  + params[(g*12+3)*16+m]*0.49f;
        const float pK2   = 0.001f + params[(g*12+4)*16+m]*0.199f;
        const float pPERC =          params[(g*12+6)*16+m]*10.f;
        const float pUZL  =          params[(g*12+7)*16+m]*100.f;
        const float oneMinusK0 = 1.f - pK0, K0UZL = pK0*pUZL;
        float SUZ = 0.001f, SLZ = 0.001f;
        for (int p = 0; p < NPHASE; ++p) {
            if (p >= 2 && p-2 < NCHUNK) {
                const int c = p-2;
                const float2* sb = &soilbuf[(c&1)*CH*64 + lane];
                float4* rd = &redbuf[(c&1)*CH*4 + gl];
                float2 rE[CH];
                #pragma unroll
                for (int s = 0; s < CH; ++s) rE[s] = sb[s*64];
                #pragma unroll
                for (int s = 0; s < CH; ++s) {
                    const float SUZ1 = SUZ + rE[s].x;
                    const float SUZ2 = fmaxf(SUZ1 - pPERC, 0.f);
                    const float PERC = SUZ1 - SUZ2;
                    const float SUZ3 = fminf(SUZ2, fmaf(SUZ2, oneMinusK0, K0UZL));
                    const float Q0 = SUZ2 - SUZ3;
                    const float Q1 = pK1 * SUZ3;
                    SUZ = SUZ3 - Q1;
                    const float SLZ1 = SLZ + PERC;
                    const float Q2 = pK2 * SLZ1;
                    SLZ = SLZ1 - Q2;
                    // mu-reduce in-register: sums land on all 16 lanes
                    const float a0 = row16_sum(Q0);
                    const float a1 = row16_sum(Q1);
                    const float a2 = row16_sum(Q2);
                    const float a3 = row16_sum(rE[s].y);
                    if (m == 0) rd[s*4] = make_float4(a0, a1, a2, a3);
                }
            }
            __syncthreads();
        }
    } else {
        // ================= W3: conv + store (1 task/lane) + x staging =========
        float wq[LENF];
        {
            const float ta  = rtwts[g*2+0] * 2.9f;
            const float tbv = rtwts[g*2+1] * 6.5f;
            const float aa = fmaxf(ta, 0.f) + 0.1f;
            const float th = fmaxf(tbv, 0.f) + 0.5f;
            const float c0v = expf(-lgammaf(aa)) * powf(th, -aa);
            float wsum = 0.f;
            #pragma unroll
            for (int k = 0; k < LENF; ++k) {
                const float tt = (float)k + 0.5f;
                wq[k] = c0v * powf(tt, aa-1.f) * expf(-tt/th);
                wsum += wq[k];
            }
            const float ws = inv16 / wsum;
            #pragma unroll
            for (int k = 0; k < LENF; ++k) wq[k] *= ws;
        }
        int rbase[3], bcol[3], lslot[3];
        #pragma unroll
        for (int j = 0; j < 3; ++j) {
            const int idx = lane + 64*j;
            const int r = idx/12, rem = idx - 12*r;
            const int gi = rem/3, ch = rem - 3*gi;
            rbase[j] = r;
            bcol[j]  = b*12 + gi*3 + ch;
            lslot[j] = r*16 + gi*4 + ch;
        }
        int st_o[5], st_g[5];
        #pragma unroll
        for (int j = 0; j < 5; ++j) {
            const int idx = lane + 64*j;
            const int tt = idx/20, cl = idx - 20*tt;
            st_o[j] = tt*OTW + cl;
            st_g[j] = tt*7500 + cl;
        }

        for (int p = 0; p < NPHASE; ++p) {
            // (a) issue next chunk's x loads early (hide HBM under epilogue)
            const bool do_stage = (p+1 < NCHUNK);
            float stg0=0.f, stg1=0.f, stg2=0.f;
            if (do_stage) {
                int r0 = (p+1)*CH + rbase[0]; r0 = (r0 < NSTEP) ? r0 : (NSTEP-1);
                int r1 = (p+1)*CH + rbase[1]; r1 = (r1 < NSTEP) ? r1 : (NSTEP-1);
                int r2 = (p+1)*CH + rbase[2]; r2 = (r2 < NSTEP) ? r2 : (NSTEP-1);
                stg0 = x[r0*4500 + bcol[0]];
                stg1 = x[r1*4500 + bcol[1]];
                stg2 = x[r2*4500 + bcol[2]];
            }
            // (b) epilogue for chunk q = p-3: one task per lane (grid gl, step m)
            const int q = p - 3;
            if (q >= 0) {
                const int nstep = (q == NCHUNK-1) ? (NSTEP - (NCHUNK-1)*CH) : CH;
                const int t = q*CH + m;
                float a0=0.f, a1=0.f, a2=0.f, a3=0.f;
                if (m < nstep) {
                    const float4 v = redbuf[(q&1)*CH*4 + m*4 + gl];
                    a0 = v.x; a1 = v.y; a2 = v.z; a3 = v.w;
                    ring[gl*64 + (t & 63)] = a0 + a1 + a2;
                }
                asm volatile("s_waitcnt lgkmcnt(0)" ::: "memory");
                if (m < nstep) {
                    float rv[LENF];
                    #pragma unroll
                    for (int k = 0; k < LENF; ++k)
                        rv[k] = ring[gl*64 + ((t - k) & 63)];
                    float accA = 0.f, accB = 0.f;
                    #pragma unroll
                    for (int k = 0; k < LENF-1; k += 2) {
                        accA = fmaf(wq[k],   rv[k],   accA);
                        accB = fmaf(wq[k+1], rv[k+1], accB);
                    }
                    accA = fmaf(wq[LENF-1], rv[LENF-1], accA);
                    float* ot = &outtile[m*OTW + gl*5];
                    ot[0] = accA + accB;
                    ot[1] = a0*inv16; ot[2] = a1*inv16;
                    ot[3] = a2*inv16; ot[4] = a3*inv16;
                }
                asm volatile("s_waitcnt lgkmcnt(0)" ::: "memory");
                const int ndw = nstep*20;
                float* ob = out + q*CH*7500 + b*20;
                #pragma unroll
                for (int j = 0; j < 5; ++j) {
                    const int idx = lane + 64*j;
                    if (idx < ndw) ob[st_g[j]] = outtile[st_o[j]];
                }
            }
            // (c) commit staged x for chunk p+1 (visible after barrier)
            if (do_stage) {
                float* xd = &xring[((p+1)%3)*CH*16];
                xd[lslot[0]] = stg0; xd[lslot[1]] = stg1; xd[lslot[2]] = stg2;
            }
            __syncthreads();
        }
    }
}

extern "C" void kernel_launch(void* const* d_in, const int* in_sizes, int n_in,
                              void* d_out, int out_size, void* d_ws, size_t ws_size,
                              hipStream_t stream)
{
    const float* x      = (const float*)d_in[0];
    const float* params = (const float*)d_in[1];
    const float* rt     = (const float*)d_in[2];
    float* out = (float*)d_out;

    dim3 grid(NGRID / 4), block(256);
    hipLaunchKernelGGL(hbv_scan_kernel, grid, block, 0, stream, x, params, rt, out);
}

// Round 19
// 60.531 us; speedup vs baseline: 1.5074x; 1.5074x over previous
//
#include <hip/hip_runtime.h>
#include <math.h>

#define NSTEP  730
#define NGRID  1500
#define LENF   15
#define PRECS  1e-5f
#define CH     16
#define NCHUNK 46                  // 45 full chunks + tail of 10
#define NPHASE (NCHUNK+3)          // 4-stage pipeline fill/drain
#define QROW   260                 // 64 float4 = 256 dw + 4 pad
#define OTW    21                  // out-tile row: 20 + 1 pad

static __device__ __forceinline__ float fexp2(float v){ return __builtin_amdgcn_exp2f(v); }
static __device__ __forceinline__ float flog2(float v){ return __builtin_amdgcn_logf(v); }

// Raw barrier with LDS-only drain. __syncthreads() emits
// `s_waitcnt vmcnt(0) expcnt(0) lgkmcnt(0)` — the vmcnt(0) forced W3 to wait
// a full HBM round-trip for its fire-and-forget stores + prefetch loads EVERY
// phase (~1500cyc: the measured per-phase overhead). Inter-wave handoffs here
// are LDS-only, so lgkmcnt(0)+s_barrier suffices; global stores retire in the
// background, x-load vmcnt waits happen naturally at the LDS commit.
#define PIPE_BARRIER() do { \
    asm volatile("s_waitcnt lgkmcnt(0)" ::: "memory"); \
    __builtin_amdgcn_sched_barrier(0); \
    __builtin_amdgcn_s_barrier(); \
    __builtin_amdgcn_sched_barrier(0); \
} while(0)

// Block = 256 threads = 4 waves = 4 pipeline stages over 4 grids, 375 blocks
// (R17 structure, best so far — only the barrier implementation changed).
//   W0 snow(c):   (SP,MW) rec -> rt      W1 soil(c-1): SM rec (exp2 chain)
//   W2 resp(c-2): (SUZ,SLZ) rec -> q     W3 epi(c-3):  reduce+conv+store, x-stage
__global__ __launch_bounds__(256, 1)
void hbv_scan_kernel(const float* __restrict__ x,       // (730,1500,3)
                     const float* __restrict__ params,  // (1500,12,16)
                     const float* __restrict__ rtwts,   // (1500,2)
                     float* __restrict__ out)           // (730,1500,5)
{
    __shared__ float  xring[3*CH*16];    //  3.0 KB (slot c%3)
    __shared__ float  rtbuf[2*CH*64];    //  8.0 KB
    __shared__ float2 soilbuf[2*CH*64];  // 16.0 KB (re, ETact)
    __shared__ float  qbuf[2*CH*QROW];   // 32.5 KB
    __shared__ float  outtile[CH*OTW];   //  1.3 KB
    __shared__ float  ring[4*64];        //  1.0 KB  (total ~62 KB, 2 blocks/CU)

    const int tid  = threadIdx.x;
    const int wid  = tid >> 6;
    const int lane = tid & 63;
    const int gl = lane >> 4, m = lane & 15;
    const int b  = blockIdx.x;
    const int g  = b*4 + gl;
    const float inv16 = 1.f/16.f;

    // prestage chunk 0 (W3) + zero conv ring, one uniform barrier
    if (wid == 3) {
        #pragma unroll
        for (int j = 0; j < 3; ++j) {
            const int idx = lane + 64*j;
            const int r = idx/12, rem = idx - 12*r;
            const int gi = rem/3, ch = rem - 3*gi;
            xring[r*16 + gi*4 + ch] = x[r*4500 + b*12 + gi*3 + ch];
        }
    }
    ring[tid & 255] = 0.f;
    PIPE_BARRIER();

    if (wid == 0) {
        // ================= W0: snow recursion =================
        const float pTT     = -2.5f + params[(g*12+8)*16+m]*5.f;
        const float pCFMAX  =  0.5f + params[(g*12+9)*16+m]*9.5f;
        const float refCoef = (params[(g*12+10)*16+m]*0.1f)*pCFMAX;
        const float pCWH    =          params[(g*12+11)*16+m]*0.2f;
        const float negCMTT = -pCFMAX*pTT;
        const float refCTT  = refCoef*pTT;
        float SP = 0.001f, MW = 0.001f;
        for (int p = 0; p < NPHASE; ++p) {
            if (p < NCHUNK) {
                const float* xb = &xring[(p%3)*CH*16 + gl*4];
                float* rb = &rtbuf[(p&1)*CH*64 + lane];
                float2 PT[CH];
                #pragma unroll
                for (int s = 0; s < CH; ++s)
                    PT[s] = *(const float2*)(xb + s*16);
                #pragma unroll
                for (int s = 0; s < CH; ++s) {
                    const float Pm = PT[s].x, Tm = PT[s].y;
                    const float RAIN    = (Tm >= pTT) ? Pm : 0.f;
                    const float meltcap = fmaxf(fmaf(pCFMAX, Tm, negCMTT), 0.f);
                    const float refcap  = fmaxf(fmaf(-refCoef, Tm, refCTT), 0.f);
                    const float SP1 = SP + (Pm - RAIN);
                    const float melt = fminf(meltcap, SP1);
                    const float MW1 = MW + melt;
                    const float refreeze = fminf(refcap, MW1);
                    SP = SP1 - melt + refreeze;
                    const float MW2 = MW1 - refreeze;
                    const float tosoil = fmaxf(fmaf(-pCWH, SP, MW2), 0.f);
                    MW = MW2 - tosoil;
                    rb[s*64] = RAIN + tosoil;
                }
            }
            PIPE_BARRIER();
        }
    } else if (wid == 1) {
        // ================= W1: soil (SM) recursion =================
        const float bb  = 1.f  + params[(g*12+0)*16+m]*5.f;
        const float pFC = 50.f + params[(g*12+1)*16+m]*950.f;
        const float pLP = 0.2f + params[(g*12+5)*16+m]*0.8f;
        const float iLPFC = 1.f/(pLP*pFC);
        const float cc = -bb * flog2(pFC);       // sw = exp2(bb*log2(SM)+cc)
        float SM = 0.001f;
        for (int p = 0; p < NPHASE; ++p) {
            if (p >= 1 && p-1 < NCHUNK) {
                const int c = p-1;
                const float* xe = &xring[(c%3)*CH*16 + gl*4 + 2];
                const float* rb = &rtbuf[(c&1)*CH*64 + lane];
                float2* sb = &soilbuf[(c&1)*CH*64 + lane];
                float rt[CH], Ev[CH];
                #pragma unroll
                for (int s = 0; s < CH; ++s) { rt[s] = rb[s*64]; Ev[s] = xe[s*16]; }
                #pragma unroll
                for (int s = 0; s < CH; ++s) {
                    const float sw  = fexp2(fmaf(bb, flog2(SM), cc));
                    const float SM1 = fmaf(-rt[s], sw, SM + rt[s]);
                    const float SM2 = fminf(SM1, pFC);
                    const float cE  = Ev[s] * iLPFC;
                    const float et  = fminf(fminf(SM2*cE, SM2), Ev[s]);  // v_min3
                    const float re  = fmaf(rt[s], sw, SM1 - SM2);
                    SM = fmaxf(fmaxf(fmaf(-SM2, cE, SM2), SM2 - Ev[s]), PRECS);
                    sb[s*64] = make_float2(re, et);
                }
            }
            PIPE_BARRIER();
        }
    } else if (wid == 2) {
        // ================= W2: response (SUZ,SLZ) recursion =================
        const float pK0   = 0.05f  + params[(g*12+2)*16+m]*0.85f;
        const float pK1   = 0.01f  + params[(g*12+3)*16+m]*0.49f;
        const float pK2   = 0.001f + params[(g*12+4)*16+m]*0.199f;
        const float pPERC =          params[(g*12+6)*16+m]*10.f;
        const float pUZL  =          params[(g*12+7)*16+m]*100.f;
        const float oneMinusK0 = 1.f - pK0, K0UZL = pK0*pUZL;
        float SUZ = 0.001f, SLZ = 0.001f;
        for (int p = 0; p < NPHASE; ++p) {
            if (p >= 2 && p-2 < NCHUNK) {
                const int c = p-2;
                const float2* sb = &soilbuf[(c&1)*CH*64 + lane];
                float* qb = &qbuf[(c&1)*CH*QROW + lane*4];
                float2 rE[CH];
                #pragma unroll
                for (int s = 0; s < CH; ++s) rE[s] = sb[s*64];
                #pragma unroll
                for (int s = 0; s < CH; ++s) {
                    const float SUZ1 = SUZ + rE[s].x;
                    const float SUZ2 = fmaxf(SUZ1 - pPERC, 0.f);
                    const float PERC = SUZ1 - SUZ2;
                    const float SUZ3 = fminf(SUZ2, fmaf(SUZ2, oneMinusK0, K0UZL));
                    const float Q0 = SUZ2 - SUZ3;
                    const float Q1 = pK1 * SUZ3;
                    SUZ = SUZ3 - Q1;
                    const float SLZ1 = SLZ + PERC;
                    const float Q2 = pK2 * SLZ1;
                    SLZ = SLZ1 - Q2;
                    *(float4*)(qb + s*QROW) = make_float4(Q0, Q1, Q2, rE[s].y);
                }
            }
            PIPE_BARRIER();
        }
    } else {
        // ================= W3: epilogue + x staging =================
        float wq[LENF];
        {
            const float ta  = rtwts[g*2+0] * 2.9f;
            const float tbv = rtwts[g*2+1] * 6.5f;
            const float aa = fmaxf(ta, 0.f) + 0.1f;
            const float th = fmaxf(tbv, 0.f) + 0.5f;
            const float c0v = expf(-lgammaf(aa)) * powf(th, -aa);
            float wsum = 0.f;
            #pragma unroll
            for (int k = 0; k < LENF; ++k) {
                const float tt = (float)k + 0.5f;
                wq[k] = c0v * powf(tt, aa-1.f) * expf(-tt/th);
                wsum += wq[k];
            }
            const float ws = inv16 / wsum;
            #pragma unroll
            for (int k = 0; k < LENF; ++k) wq[k] *= ws;
        }
        int rbase[3], bcol[3], lslot[3];
        #pragma unroll
        for (int j = 0; j < 3; ++j) {
            const int idx = lane + 64*j;
            const int r = idx/12, rem = idx - 12*r;
            const int gi = rem/3, ch = rem - 3*gi;
            rbase[j] = r;
            bcol[j]  = b*12 + gi*3 + ch;
            lslot[j] = r*16 + gi*4 + ch;
        }
        int st_o[5], st_g[5];
        #pragma unroll
        for (int j = 0; j < 5; ++j) {
            const int idx = lane + 64*j;
            const int tt = idx/20, cl = idx - 20*tt;
            st_o[j] = tt*OTW + cl;
            st_g[j] = tt*7500 + cl;
        }

        for (int p = 0; p < NPHASE; ++p) {
            // (a) issue next chunk's x loads early (hide HBM under epilogue)
            const bool do_stage = (p+1 < NCHUNK);
            float stg0=0.f, stg1=0.f, stg2=0.f;
            if (do_stage) {
                int r0 = (p+1)*CH + rbase[0]; r0 = (r0 < NSTEP) ? r0 : (NSTEP-1);
                int r1 = (p+1)*CH + rbase[1]; r1 = (r1 < NSTEP) ? r1 : (NSTEP-1);
                int r2 = (p+1)*CH + rbase[2]; r2 = (r2 < NSTEP) ? r2 : (NSTEP-1);
                stg0 = x[r0*4500 + bcol[0]];
                stg1 = x[r1*4500 + bcol[1]];
                stg2 = x[r2*4500 + bcol[2]];
            }
            // (b) epilogue for chunk q = p-3
            const int q = p - 3;
            if (q >= 0) {
                const int nstep = (q == NCHUNK-1) ? (NSTEP - (NCHUNK-1)*CH) : CH;
                const float* qb = &qbuf[(q&1)*CH*QROW];
                const int t = q*CH + m;
                float a0=0.f, a1=0.f, a2=0.f, a3=0.f;
                if (m < nstep) {
                    float4 v[16];
                    #pragma unroll
                    for (int i = 0; i < 16; ++i)
                        v[i] = *(const float4*)&qb[m*QROW + gl*64 + i*4];
                    float4 s0 = v[0], s1 = v[1], s2 = v[2], s3 = v[3];
                    #pragma unroll
                    for (int i = 4; i < 16; i += 4) {
                        s0.x+=v[i].x;   s0.y+=v[i].y;   s0.z+=v[i].z;   s0.w+=v[i].w;
                        s1.x+=v[i+1].x; s1.y+=v[i+1].y; s1.z+=v[i+1].z; s1.w+=v[i+1].w;
                        s2.x+=v[i+2].x; s2.y+=v[i+2].y; s2.z+=v[i+2].z; s2.w+=v[i+2].w;
                        s3.x+=v[i+3].x; s3.y+=v[i+3].y; s3.z+=v[i+3].z; s3.w+=v[i+3].w;
                    }
                    a0 = (s0.x+s1.x) + (s2.x+s3.x);
                    a1 = (s0.y+s1.y) + (s2.y+s3.y);
                    a2 = (s0.z+s1.z) + (s2.z+s3.z);
                    a3 = (s0.w+s1.w) + (s2.w+s3.w);
                    ring[gl*64 + (t & 63)] = a0 + a1 + a2;
                }
                asm volatile("s_waitcnt lgkmcnt(0)" ::: "memory");
                if (m < nstep) {
                    float rv[LENF];
                    #pragma unroll
                    for (int k = 0; k < LENF; ++k)
                        rv[k] = ring[gl*64 + ((t - k) & 63)];
                    float accA = 0.f, accB = 0.f;
                    #pragma unroll
                    for (int k = 0; k < LENF-1; k += 2) {
                        accA = fmaf(wq[k],   rv[k],   accA);
                        accB = fmaf(wq[k+1], rv[k+1], accB);
                    }
                    accA = fmaf(wq[LENF-1], rv[LENF-1], accA);
                    float* ot = &outtile[m*OTW + gl*5];
                    ot[0] = accA + accB;
                    ot[1] = a0*inv16; ot[2] = a1*inv16;
                    ot[3] = a2*inv16; ot[4] = a3*inv16;
                }
                asm volatile("s_waitcnt lgkmcnt(0)" ::: "memory");
                const int ndw = nstep*20;
                float* ob = out + q*CH*7500 + b*20;
                #pragma unroll
                for (int j = 0; j < 5; ++j) {
                    const int idx = lane + 64*j;
                    if (idx < ndw) ob[st_g[j]] = outtile[st_o[j]];
                }
            }
            // (c) commit staged x for chunk p+1 (visible after barrier)
            if (do_stage) {
                float* xd = &xring[((p+1)%3)*CH*16];
                xd[lslot[0]] = stg0; xd[lslot[1]] = stg1; xd[lslot[2]] = stg2;
            }
            PIPE_BARRIER();
        }
    }
}

extern "C" void kernel_launch(void* const* d_in, const int* in_sizes, int n_in,
                              void* d_out, int out_size, void* d_ws, size_t ws_size,
                              hipStream_t stream)
{
    const float* x      = (const float*)d_in[0];
    const float* params = (const float*)d_in[1];
    const float* rt     = (const float*)d_in[2];
    float* out = (float*)d_out;

    dim3 grid(NGRID / 4), block(256);
    hipLaunchKernelGGL(hbv_scan_kernel, grid, block, 0, stream, x, params, rt, out);
}